// Round 3
// baseline (312.183 us; speedup 1.0000x reference)
//
#include <hip/hip_runtime.h>
#include <hip/hip_bf16.h>
#include <math.h>

typedef __attribute__((ext_vector_type(8))) short bf16x8;
typedef __attribute__((ext_vector_type(4))) float f32x4;
typedef __attribute__((ext_vector_type(2))) unsigned u32x2;

__device__ inline unsigned bfraw(float f) {
    union { float f; unsigned u; } x; x.f = f;
    return x.u + 0x8000u;            // round-to-nearest, ties-away
}
__device__ inline short f2bf(float f) { return (short)(bfraw(f) >> 16); }
__device__ inline unsigned pk2bf(float lo, float hi) {
    return (bfraw(lo) >> 16) | (bfraw(hi) & 0xFFFF0000u);
}
__device__ inline float fast_exp2(float x) {
#if __has_builtin(__builtin_amdgcn_exp2f)
    return __builtin_amdgcn_exp2f(x);
#else
    return exp2f(x);
#endif
}
#define SCQ 0.18033688011112042f     // 0.125 * log2(e), folded into Q

// ---------------------------------------------------------------------------
// Kernel 1: qkv = array(4096x256) @ Wqkv(256x3072).
//   Q -> (B,H,N,64) bf16, PRE-SCALED by SCQ
//   K -> (B,H,N,64) bf16
//   V -> (B,H,64,N) bf16 (TRANSPOSED so attn PV B-fragments are contiguous)
// Staging uses single ds_write_b128 per thread (conflict-free pads).
// ---------------------------------------------------------------------------
__global__ __launch_bounds__(256) void qkv_kernel(
        const float* __restrict__ A, const float* __restrict__ W,
        short* __restrict__ Qb, short* __restrict__ Kb, short* __restrict__ Vt) {
    __shared__ short As[64 * 40];    // As[m][k], pad 40
    __shared__ short Bs[64 * 36];    // Bs[n][k], pad 36 (stride 18 dw: 16 distinct banks)
    int m0 = blockIdx.x * 64;
    int n0 = blockIdx.y * 64;
    int t = threadIdx.x;
    int wave = t >> 6, lane = t & 63;
    int quad = lane >> 4, l16 = lane & 15;
    f32x4 acc[4] = {};
    for (int k0 = 0; k0 < 256; k0 += 32) {
        __syncthreads();
        {   // A tile 64x32: thread -> row t>>2, cols (t&3)*8..+7 (32B contig loads)
            int row = t >> 2, col = (t & 3) * 8;
            const float* src = A + (size_t)(m0 + row) * 256 + k0 + col;
            f32x4 a0 = *(const f32x4*)src;
            f32x4 a1 = *(const f32x4*)(src + 4);
            bf16x8 v;
#pragma unroll
            for (int j = 0; j < 4; ++j) { v[j] = f2bf(a0[j]); v[4 + j] = f2bf(a1[j]); }
            *(bf16x8*)&As[row * 40 + col] = v;
        }
        {   // B tile 32x64 -> Bs[n][k]: thread n=t&63, k=(t>>6)*8..+7
            int n = t & 63, kk = (t >> 6) * 8;
            const float* src = W + (size_t)(k0 + kk) * 3072 + n0 + n;
            bf16x8 v;
#pragma unroll
            for (int j = 0; j < 8; ++j) v[j] = f2bf(src[(size_t)j * 3072]);
            *(bf16x8*)&Bs[n * 36 + kk] = v;
        }
        __syncthreads();
        bf16x8 af = *(const bf16x8*)&As[(wave * 16 + l16) * 40 + quad * 8];
#pragma unroll
        for (int c = 0; c < 4; ++c) {
            bf16x8 bfr = *(const bf16x8*)&Bs[(c * 16 + l16) * 36 + quad * 8];
            acc[c] = __builtin_amdgcn_mfma_f32_16x16x32_bf16(af, bfr, acc[c], 0, 0, 0);
        }
    }
    // epilogue: block-uniform sel/h (n0 is a multiple of 64)
    int sel = n0 >> 10;
    int h = (n0 & 1023) >> 6;
    int b = m0 >> 11;
    int n_base = (m0 & 2047) + wave * 16 + quad * 4;
    if (sel == 2) {
        // V transposed: Vt[((b*16+h)*64 + dim)*2048 + n], 4 consecutive n packed
#pragma unroll
        for (int c = 0; c < 4; ++c) {
            int dim = c * 16 + l16;
            u32x2 pk;
            pk[0] = pk2bf(acc[c][0], acc[c][1]);
            pk[1] = pk2bf(acc[c][2], acc[c][3]);
            *(u32x2*)&Vt[(((size_t)(b * 16 + h) * 64 + dim) << 11) + n_base] = pk;
        }
    } else {
        short* dst = (sel == 0) ? Qb : Kb;
        float sc = (sel == 0) ? SCQ : 1.0f;
#pragma unroll
        for (int c = 0; c < 4; ++c) {
            int dim = c * 16 + l16;
#pragma unroll
            for (int r = 0; r < 4; ++r) {
                dst[(((size_t)(b * 16 + h) * 2048 + n_base + r) << 6) + dim] =
                    f2bf(acc[c][r] * sc);
            }
        }
    }
}

// ---------------------------------------------------------------------------
// Kernel 2: flash attention, S^T formulation, NO LDS / NO barriers / NO shfl
// in the loop. m=0 softmax (scores are O(0.3); fp32 exp2 range is ample).
// Lane holds P[q=l16][key=quad*8+j] directly as the PV A-fragment.
// ---------------------------------------------------------------------------
__global__ __launch_bounds__(256) void attn_kernel(
        const short* __restrict__ Qb, const short* __restrict__ Kb,
        const short* __restrict__ Vt, short* __restrict__ AO) {
    int bh = blockIdx.y;
    int qt = blockIdx.x;
    int b = bh >> 4, h = bh & 15;
    int t = threadIdx.x, wave = t >> 6, lane = t & 63;
    int quad = lane >> 4, l16 = lane & 15;
    const short* Qp = Qb + (size_t)bh * 2048 * 64;
    const short* Kp = Kb + (size_t)bh * 2048 * 64;
    const short* Vp = Vt + (size_t)bh * 64 * 2048;   // [dim][key]
    int q0 = qt * 64 + wave * 16;
    bf16x8 qf0 = *(const bf16x8*)&Qp[(q0 + l16) * 64 + quad * 8];
    bf16x8 qf1 = *(const bf16x8*)&Qp[(q0 + l16) * 64 + 32 + quad * 8];
    f32x4 o[4] = {};
    float lsum = 0.f;
    int keyl = ((l16 >> 2) * 8) + (l16 & 3);   // permuted key row base

#pragma unroll 2
    for (int kt = 0; kt < 32; ++kt) {
        int kb = kt * 64;
        bf16x8 kc[8], vc[8];
#pragma unroll
        for (int hh = 0; hh < 2; ++hh)
#pragma unroll
            for (int ab = 0; ab < 2; ++ab) {
                const short* kp = Kp + ((kb + hh * 32 + keyl + ab * 4) << 6) + quad * 8;
                kc[(hh * 2 + ab) * 2]     = *(const bf16x8*)kp;
                kc[(hh * 2 + ab) * 2 + 1] = *(const bf16x8*)(kp + 32);
            }
#pragma unroll
        for (int hh = 0; hh < 2; ++hh)
#pragma unroll
            for (int dt = 0; dt < 4; ++dt)
                vc[hh * 4 + dt] =
                    *(const bf16x8*)&Vp[(dt * 16 + l16) * 2048 + kb + hh * 32 + quad * 8];

        f32x4 s[4];
#pragma unroll
        for (int i = 0; i < 4; ++i) {
            f32x4 z = {};
            z = __builtin_amdgcn_mfma_f32_16x16x32_bf16(kc[2 * i], qf0, z, 0, 0, 0);
            z = __builtin_amdgcn_mfma_f32_16x16x32_bf16(kc[2 * i + 1], qf1, z, 0, 0, 0);
            s[i] = z;   // already scaled (Q pre-scaled by SCQ)
        }
        bf16x8 pa[2];
#pragma unroll
        for (int hh = 0; hh < 2; ++hh)
#pragma unroll
            for (int ab = 0; ab < 2; ++ab) {
                float p0 = fast_exp2(s[hh * 2 + ab][0]);
                float p1 = fast_exp2(s[hh * 2 + ab][1]);
                float p2 = fast_exp2(s[hh * 2 + ab][2]);
                float p3 = fast_exp2(s[hh * 2 + ab][3]);
                lsum += (p0 + p1) + (p2 + p3);
                unsigned lo = pk2bf(p0, p1), hi = pk2bf(p2, p3);
                pa[hh][ab * 4 + 0] = (short)(lo & 0xFFFF);
                pa[hh][ab * 4 + 1] = (short)(lo >> 16);
                pa[hh][ab * 4 + 2] = (short)(hi & 0xFFFF);
                pa[hh][ab * 4 + 3] = (short)(hi >> 16);
            }
#pragma unroll
        for (int hh = 0; hh < 2; ++hh)
#pragma unroll
            for (int dt = 0; dt < 4; ++dt)
                o[dt] = __builtin_amdgcn_mfma_f32_16x16x32_bf16(pa[hh], vc[hh * 4 + dt],
                                                                o[dt], 0, 0, 0);
    }
    // epilogue: reduce l over quads, broadcast 1/l to C-layout rows
    lsum += __shfl_xor(lsum, 16, 64);
    lsum += __shfl_xor(lsum, 32, 64);
    float inv = 1.0f / lsum;
    float rT[4];
#pragma unroll
    for (int r = 0; r < 4; ++r) rT[r] = __shfl(inv, quad * 4 + r, 64);
#pragma unroll
    for (int dt = 0; dt < 4; ++dt) {
#pragma unroll
        for (int r = 0; r < 4; ++r) {
            int qrow = q0 + quad * 4 + r;
            AO[((size_t)(b * 2048 + qrow) << 10) + h * 64 + dt * 16 + l16] =
                f2bf(o[dt][r] * rT[r]);
        }
    }
}

// ---------------------------------------------------------------------------
// Kernel 3: out = AO(4096x1024 bf16) @ Wout(1024x64 fp32) -> fp32.
// 256 blocks (M-tile 16), 4 waves split K (256 each), Wout B-fragments
// transposed into registers once, LDS tree-reduce, coalesced f32x4 store.
// ---------------------------------------------------------------------------
__global__ __launch_bounds__(256) void out_kernel(
        const short* __restrict__ AO, const float* __restrict__ W,
        float* __restrict__ Out) {
    __shared__ float red[4][16][64];   // 16 KB
    int m0 = blockIdx.x * 16;
    int t = threadIdx.x, wave = t >> 6, lane = t & 63;
    int quad = lane >> 4, l16 = lane & 15;
    int kbase = wave * 256;
    bf16x8 bw[4][8];
#pragma unroll
    for (int c = 0; c < 4; ++c)
#pragma unroll
        for (int it = 0; it < 8; ++it) {
            int kb = kbase + it * 32 + quad * 8;
            const float* wp = W + (size_t)kb * 64 + c * 16 + l16;
#pragma unroll
            for (int j = 0; j < 8; ++j) bw[c][it][j] = f2bf(wp[(size_t)j * 64]);
        }
    f32x4 acc[4] = {};
#pragma unroll
    for (int it = 0; it < 8; ++it) {
        bf16x8 af = *(const bf16x8*)&AO[(size_t)(m0 + l16) * 1024 + kbase + it * 32 + quad * 8];
#pragma unroll
        for (int c = 0; c < 4; ++c)
            acc[c] = __builtin_amdgcn_mfma_f32_16x16x32_bf16(af, bw[c][it], acc[c], 0, 0, 0);
    }
#pragma unroll
    for (int c = 0; c < 4; ++c)
#pragma unroll
        for (int r = 0; r < 4; ++r)
            red[wave][quad * 4 + r][c * 16 + l16] = acc[c][r];
    __syncthreads();
    int i = t * 4;                 // 1024 outputs per block
    int row = i >> 6, col = i & 63;
    f32x4 v = *(const f32x4*)&red[0][row][col];
    v += *(const f32x4*)&red[1][row][col];
    v += *(const f32x4*)&red[2][row][col];
    v += *(const f32x4*)&red[3][row][col];
    *(f32x4*)&Out[(size_t)(m0 + row) * 64 + col] = v;
}

// ---------------------------------------------------------------------------
extern "C" void kernel_launch(void* const* d_in, const int* in_sizes, int n_in,
                              void* d_out, int out_size, void* d_ws, size_t ws_size,
                              hipStream_t stream) {
    const float* A    = (const float*)d_in[0];   // (2,2048,256)
    const float* Wqkv = (const float*)d_in[1];   // (256,3072)
    const float* Wout = (const float*)d_in[2];   // (1024,64)
    float* Out = (float*)d_out;                  // (2,2048,64) fp32

    short* ws = (short*)d_ws;
    short* Qb = ws;                  // 4M shorts each
    short* Kb = ws + 4194304;
    short* Vt = ws + 8388608;        // (B,H,64,2048)
    short* AO = ws + 12582912;       // (4096,1024)

    dim3 g1(64, 48);
    hipLaunchKernelGGL(qkv_kernel, g1, dim3(256), 0, stream, A, Wqkv, Qb, Kb, Vt);
    dim3 g2(32, 32);
    hipLaunchKernelGGL(attn_kernel, g2, dim3(256), 0, stream, Qb, Kb, Vt, AO);
    hipLaunchKernelGGL(out_kernel, dim3(256), dim3(256), 0, stream, AO, Wout, Out);
}

// Round 4
// 145.301 us; speedup vs baseline: 2.1485x; 2.1485x over previous
//
#include <hip/hip_runtime.h>
#include <hip/hip_bf16.h>
#include <math.h>

typedef __attribute__((ext_vector_type(8))) short bf16x8;
typedef __attribute__((ext_vector_type(4))) float f32x4;
typedef __attribute__((ext_vector_type(4))) unsigned u32x4;
typedef __attribute__((ext_vector_type(2))) unsigned u32x2;

union bfpack { u32x4 u; bf16x8 h; };

__device__ inline unsigned bfraw(float f) {
    union { float f; unsigned u; } x; x.f = f;
    return x.u + 0x8000u;            // round-half-up to bf16
}
__device__ inline short f2bf(float f) { return (short)(bfraw(f) >> 16); }
// pack two floats to bf16x2 in one v_perm
__device__ inline unsigned pkbf(float lo, float hi) {
    return __builtin_amdgcn_perm(bfraw(hi), bfraw(lo), 0x07060302);
}
__device__ inline float fast_exp2(float x) {
#if __has_builtin(__builtin_amdgcn_exp2f)
    return __builtin_amdgcn_exp2f(x);
#else
    return exp2f(x);
#endif
}
__device__ inline void gl_lds16(const short* g, short* l) {
    __builtin_amdgcn_global_load_lds(
        (const __attribute__((address_space(1))) unsigned*)g,
        (__attribute__((address_space(3))) unsigned*)l, 16, 0, 0);
}
#define SCQ 0.18033688011112042f     // 0.125 * log2(e), folded into Q

// ---------------------------------------------------------------------------
// Kernel 1: qkv = array(4096x256) @ Wqkv(256x3072). 128x128 tiles.
//   Q -> (B,H,N,64) bf16 pre-scaled by SCQ; K -> (B,H,N,64); V -> (B,H,64,N).
// ---------------------------------------------------------------------------
__global__ __launch_bounds__(256) void qkv_kernel(
        const float* __restrict__ A, const float* __restrict__ W,
        short* __restrict__ Qb, short* __restrict__ Kb, short* __restrict__ Vt) {
    __shared__ short As[128 * 40];   // As[m][k 0..31], pad 8, plain
    __shared__ short Bs[128 * 40];   // Bs[n][k 0..31], 16B chunks XOR (n&3)
    int m0 = blockIdx.x * 128;
    int n0 = blockIdx.y * 128;
    int t = threadIdx.x;
    int wave = t >> 6, lane = t & 63;
    int quad = lane >> 4, l16 = lane & 15;
    f32x4 acc[2][8] = {};
    for (int k0 = 0; k0 < 256; k0 += 32) {
        __syncthreads();
        {   // A: 128 rows x 32 k, fp32->bf16, 2x ds_write_b128
            int row = t >> 1, kh = (t & 1) * 16;
            const float* src = A + (size_t)(m0 + row) * 256 + k0 + kh;
            f32x4 a0 = ((const f32x4*)src)[0], a1 = ((const f32x4*)src)[1],
                  a2 = ((const f32x4*)src)[2], a3 = ((const f32x4*)src)[3];
            bfpack v0, v1;
            v0.u[0] = pkbf(a0[0], a0[1]); v0.u[1] = pkbf(a0[2], a0[3]);
            v0.u[2] = pkbf(a1[0], a1[1]); v0.u[3] = pkbf(a1[2], a1[3]);
            v1.u[0] = pkbf(a2[0], a2[1]); v1.u[1] = pkbf(a2[2], a2[3]);
            v1.u[2] = pkbf(a3[0], a3[1]); v1.u[3] = pkbf(a3[2], a3[3]);
            *(bf16x8*)&As[row * 40 + kh]     = v0.h;
            *(bf16x8*)&As[row * 40 + kh + 8] = v1.h;
        }
        {   // B: 32k x 128n -> Bs[n][k], chunk-swizzled
            int n = t & 127, kh = (t >> 7) * 16;
            const float* src = W + (size_t)(k0 + kh) * 3072 + n0 + n;
#pragma unroll
            for (int cc = 0; cc < 2; ++cc) {
                int clog = (kh >> 3) + cc;
                int pos = clog ^ (n & 3);
                unsigned* dst = (unsigned*)&Bs[n * 40 + pos * 8];
#pragma unroll
                for (int jj = 0; jj < 4; ++jj) {
                    float w0 = src[(size_t)(cc * 8 + 2 * jj) * 3072];
                    float w1 = src[(size_t)(cc * 8 + 2 * jj + 1) * 3072];
                    dst[jj] = pkbf(w0, w1);
                }
            }
        }
        __syncthreads();
        bf16x8 af[2], bfr[8];
#pragma unroll
        for (int s = 0; s < 2; ++s)
            af[s] = *(const bf16x8*)&As[(wave * 32 + s * 16 + l16) * 40 + quad * 8];
#pragma unroll
        for (int c = 0; c < 8; ++c) {
            int n = c * 16 + l16;
            bfr[c] = *(const bf16x8*)&Bs[n * 40 + (quad ^ (n & 3)) * 8];
        }
#pragma unroll
        for (int s = 0; s < 2; ++s)
#pragma unroll
            for (int c = 0; c < 8; ++c)
                acc[s][c] = __builtin_amdgcn_mfma_f32_16x16x32_bf16(af[s], bfr[c],
                                                                    acc[s][c], 0, 0, 0);
    }
    int sel = n0 >> 10;                 // 128-tiles never straddle Q/K/V
    int b = m0 >> 11;
    int nb = (m0 & 2047) + wave * 32;
#pragma unroll
    for (int s = 0; s < 2; ++s) {
#pragma unroll
        for (int c = 0; c < 8; ++c) {
            int gc = n0 + c * 16 + l16;
            int h = (gc >> 6) & 15, dim = gc & 63;
            int n_base = nb + s * 16 + quad * 4;
            if (sel == 2) {
                u32x2 pk;
                pk[0] = pkbf(acc[s][c][0], acc[s][c][1]);
                pk[1] = pkbf(acc[s][c][2], acc[s][c][3]);
                *(u32x2*)&Vt[(((size_t)(b * 16 + h) * 64 + dim) << 11) + n_base] = pk;
            } else {
                short* dst = (sel == 0) ? Qb : Kb;
                float sc = (sel == 0) ? SCQ : 1.0f;
#pragma unroll
                for (int r = 0; r < 4; ++r)
                    dst[(((size_t)(b * 16 + h) * 2048 + n_base + r) << 6) + dim] =
                        f2bf(acc[s][c][r] * sc);
            }
        }
    }
}

// ---------------------------------------------------------------------------
// Kernel 2: flash attention. S^T trick + m=0 softmax + l-via-ones-MFMA.
// K/V tiles staged via global_load_lds with 16B-chunk XOR swizzle; dbuf.
// Wave owns 32 queries; grid (16,32)=512 blocks (2/CU).
// ---------------------------------------------------------------------------
__global__ __launch_bounds__(256, 2) void attn_kernel(
        const short* __restrict__ Qb, const short* __restrict__ Kb,
        const short* __restrict__ Vt, short* __restrict__ AO) {
    __shared__ short KT[2][64 * 64];   // [key][dim] chunk-swizzled
    __shared__ short VT[2][64 * 64];   // [dim][key] chunk-swizzled
    int bh = blockIdx.y, qt = blockIdx.x;
    int t = threadIdx.x, wave = t >> 6, lane = t & 63;
    int quad = lane >> 4, l16 = lane & 15;
    const short* Qp = Qb + (size_t)bh * (2048 * 64);
    const short* Kp = Kb + (size_t)bh * (2048 * 64);
    const short* Vp = Vt + (size_t)bh * (64 * 2048);
    int q0 = qt * 128 + wave * 32;

    bf16x8 qf[2][2];
#pragma unroll
    for (int sq = 0; sq < 2; ++sq) {
        const short* qp = Qp + (size_t)(q0 + sq * 16 + l16) * 64 + quad * 8;
        qf[sq][0] = *(const bf16x8*)qp;
        qf[sq][1] = *(const bf16x8*)(qp + 32);
    }
    // ---- staging addresses (per-lane global, wave-uniform LDS) ----
    int r8 = lane >> 3, p8 = lane & 7;
    int kr0 = wave * 16 + r8, kr1 = kr0 + 8;
    int swz0 = (kr0 & 3) | (((kr0 >> 3) & 1) << 2);
    int swz1 = (kr1 & 3) | (((kr1 >> 3) & 1) << 2);
    const short* gk0 = Kp + kr0 * 64 + (p8 ^ swz0) * 8;
    const short* gk1 = Kp + kr1 * 64 + (p8 ^ swz1) * 8;
    const short* gv0 = Vp + kr0 * 2048 + (p8 ^ (kr0 & 7)) * 8;
    const short* gv1 = Vp + kr1 * 2048 + (p8 ^ (kr1 & 7)) * 8;
    int ldsk0 = wave * 1024, ldsk1 = wave * 1024 + 512;
    // ---- fragment read offsets (loop-invariant) ----
    int swzk = (l16 & 3) | (((l16 >> 2) & 1) << 2);
    int krd = ((l16 >> 2) * 8 + (l16 & 3)) * 64;
    int koff0 = krd + ((quad ^ swzk) * 8);          // dims 0..31
    int koff1 = krd + (((quad + 4) ^ swzk) * 8);    // dims 32..63
    int voff0 = l16 * 64 + ((quad ^ (l16 & 7)) * 8);        // keys 0..31
    int voff1 = l16 * 64 + (((quad + 4) ^ (l16 & 7)) * 8);  // keys 32..63

    f32x4 o[2][4] = {};
    f32x4 ol[2] = {};
    bf16x8 ones = {(short)0x3F80, (short)0x3F80, (short)0x3F80, (short)0x3F80,
                   (short)0x3F80, (short)0x3F80, (short)0x3F80, (short)0x3F80};

    // prefetch tile 0
    gl_lds16(gk0, &KT[0][ldsk0]);
    gl_lds16(gk1, &KT[0][ldsk1]);
    gl_lds16(gv0, &VT[0][ldsk0]);
    gl_lds16(gv1, &VT[0][ldsk1]);

    for (int kt = 0; kt < 32; ++kt) {
        __syncthreads();                       // drains prefetch (vmcnt) + sync
        if (kt + 1 < 32) {
            int buf = (kt + 1) & 1;
            gl_lds16(gk0 + (size_t)(kt + 1) * 4096, &KT[buf][ldsk0]);
            gl_lds16(gk1 + (size_t)(kt + 1) * 4096, &KT[buf][ldsk1]);
            gl_lds16(gv0 + (kt + 1) * 64, &VT[buf][ldsk0]);
            gl_lds16(gv1 + (kt + 1) * 64, &VT[buf][ldsk1]);
        }
        const short* kb = &KT[kt & 1][0];
        const short* vb = &VT[kt & 1][0];
        bf16x8 kc[8], vc[8];
#pragma unroll
        for (int hh = 0; hh < 2; ++hh)
#pragma unroll
            for (int ab = 0; ab < 2; ++ab) {
                kc[(hh * 2 + ab) * 2 + 0] = *(const bf16x8*)&kb[koff0 + ab * 256 + hh * 2048];
                kc[(hh * 2 + ab) * 2 + 1] = *(const bf16x8*)&kb[koff1 + ab * 256 + hh * 2048];
            }
#pragma unroll
        for (int hh = 0; hh < 2; ++hh)
#pragma unroll
            for (int dt = 0; dt < 4; ++dt)
                vc[hh * 4 + dt] = *(const bf16x8*)&vb[(hh ? voff1 : voff0) + dt * 1024];

#pragma unroll
        for (int sq = 0; sq < 2; ++sq) {
            f32x4 s[4];
#pragma unroll
            for (int i = 0; i < 4; ++i) {
                f32x4 z = {};
                z = __builtin_amdgcn_mfma_f32_16x16x32_bf16(kc[2 * i], qf[sq][0], z, 0, 0, 0);
                z = __builtin_amdgcn_mfma_f32_16x16x32_bf16(kc[2 * i + 1], qf[sq][1], z, 0, 0, 0);
                s[i] = z;
            }
            bfpack pa0, pa1;
#pragma unroll
            for (int ab = 0; ab < 2; ++ab) {
                float p0 = fast_exp2(s[ab][0]),     p1 = fast_exp2(s[ab][1]);
                float p2 = fast_exp2(s[ab][2]),     p3 = fast_exp2(s[ab][3]);
                float q0e = fast_exp2(s[2 + ab][0]), q1e = fast_exp2(s[2 + ab][1]);
                float q2e = fast_exp2(s[2 + ab][2]), q3e = fast_exp2(s[2 + ab][3]);
                pa0.u[ab * 2 + 0] = pkbf(p0, p1);
                pa0.u[ab * 2 + 1] = pkbf(p2, p3);
                pa1.u[ab * 2 + 0] = pkbf(q0e, q1e);
                pa1.u[ab * 2 + 1] = pkbf(q2e, q3e);
            }
            ol[sq] = __builtin_amdgcn_mfma_f32_16x16x32_bf16(pa0.h, ones, ol[sq], 0, 0, 0);
            ol[sq] = __builtin_amdgcn_mfma_f32_16x16x32_bf16(pa1.h, ones, ol[sq], 0, 0, 0);
#pragma unroll
            for (int dt = 0; dt < 4; ++dt) {
                o[sq][dt] = __builtin_amdgcn_mfma_f32_16x16x32_bf16(pa0.h, vc[dt],
                                                                    o[sq][dt], 0, 0, 0);
                o[sq][dt] = __builtin_amdgcn_mfma_f32_16x16x32_bf16(pa1.h, vc[4 + dt],
                                                                    o[sq][dt], 0, 0, 0);
            }
        }
    }
    // epilogue: l sits in the same C-layout rows as O -> no shuffles
#pragma unroll
    for (int sq = 0; sq < 2; ++sq) {
        f32x4 inv;
#pragma unroll
        for (int r = 0; r < 4; ++r) inv[r] = 1.0f / ol[sq][r];
#pragma unroll
        for (int dt = 0; dt < 4; ++dt)
#pragma unroll
            for (int r = 0; r < 4; ++r) {
                int qrow = q0 + sq * 16 + quad * 4 + r;
                AO[((size_t)bh * 2048 + qrow) * 64 + dt * 16 + l16] =
                    f2bf(o[sq][dt][r] * inv[r]);
            }
    }
}

// ---------------------------------------------------------------------------
// Kernel 3: out[b,n,:] = sum_h AO[b,h,n,:] @ Wout[h*64:+64,:]. M-tile 64.
// ---------------------------------------------------------------------------
__global__ __launch_bounds__(256) void out_kernel(
        const short* __restrict__ AO, const float* __restrict__ W,
        float* __restrict__ Out) {
    __shared__ short As[64 * 72];   // [m][k], chunk-swizzled by (row&7)
    __shared__ short Bs[64 * 72];   // [n][k], chunk-swizzled by (n&7)
    int m0 = blockIdx.x * 64;
    int t = threadIdx.x, wave = t >> 6, lane = t & 63;
    int quad = lane >> 4, l16 = lane & 15;
    int b = m0 >> 11;
    f32x4 acc[4] = {};
    for (int h = 0; h < 16; ++h) {
        __syncthreads();
        {   // A tile: 64 rows x 64 k from AO (bf16), swizzled b128 writes
            int row = t >> 2, kh = (t & 3) * 16;
            const short* src = AO + ((size_t)(b * 16 + h) * 2048 + (m0 & 2047) + row) * 64 + kh;
            bf16x8 w0 = *(const bf16x8*)src;
            bf16x8 w1 = *(const bf16x8*)(src + 8);
            int c0 = (kh >> 3), c1 = c0 + 1;
            *(bf16x8*)&As[row * 72 + (c0 ^ (row & 7)) * 8] = w0;
            *(bf16x8*)&As[row * 72 + (c1 ^ (row & 7)) * 8] = w1;
        }
        {   // B tile: Wout rows h*64..+63 (fp32) -> Bs[n][k] swizzled
            int n = t & 63, kh = (t >> 6) * 16;
            const float* src = W + (size_t)(h * 64 + kh) * 64 + n;
#pragma unroll
            for (int cc = 0; cc < 2; ++cc) {
                int clog = (kh >> 3) + cc;
                unsigned* dst = (unsigned*)&Bs[n * 72 + (clog ^ (n & 7)) * 8];
#pragma unroll
                for (int jj = 0; jj < 4; ++jj) {
                    float w0 = src[(size_t)(cc * 8 + 2 * jj) * 64];
                    float w1 = src[(size_t)(cc * 8 + 2 * jj + 1) * 64];
                    dst[jj] = pkbf(w0, w1);
                }
            }
        }
        __syncthreads();
        bf16x8 af[2], bfr[4][2];
        int arow = wave * 16 + l16;
#pragma unroll
        for (int kf = 0; kf < 2; ++kf)
            af[kf] = *(const bf16x8*)&As[arow * 72 + (((quad + 4 * kf) ^ (arow & 7)) * 8)];
#pragma unroll
        for (int c = 0; c < 4; ++c) {
            int n = c * 16 + l16;
#pragma unroll
            for (int kf = 0; kf < 2; ++kf)
                bfr[c][kf] = *(const bf16x8*)&Bs[n * 72 + (((quad + 4 * kf) ^ (n & 7)) * 8)];
        }
#pragma unroll
        for (int c = 0; c < 4; ++c) {
            acc[c] = __builtin_amdgcn_mfma_f32_16x16x32_bf16(af[0], bfr[c][0], acc[c], 0, 0, 0);
            acc[c] = __builtin_amdgcn_mfma_f32_16x16x32_bf16(af[1], bfr[c][1], acc[c], 0, 0, 0);
        }
    }
#pragma unroll
    for (int c = 0; c < 4; ++c)
#pragma unroll
        for (int r = 0; r < 4; ++r) {
            int gm = m0 + wave * 16 + quad * 4 + r;
            Out[((size_t)gm << 6) + c * 16 + l16] = acc[c][r];
        }
}

// ---------------------------------------------------------------------------
extern "C" void kernel_launch(void* const* d_in, const int* in_sizes, int n_in,
                              void* d_out, int out_size, void* d_ws, size_t ws_size,
                              hipStream_t stream) {
    const float* A    = (const float*)d_in[0];   // (2,2048,256)
    const float* Wqkv = (const float*)d_in[1];   // (256,3072)
    const float* Wout = (const float*)d_in[2];   // (1024,64)
    float* Out = (float*)d_out;                  // (2,2048,64) fp32

    short* ws = (short*)d_ws;
    short* Qb = ws;                  // (B,H,N,64)
    short* Kb = ws + 4194304;        // (B,H,N,64)
    short* Vt = ws + 8388608;        // (B,H,64,N)
    short* AO = ws + 12582912;       // (B,H,N,64)

    hipLaunchKernelGGL(qkv_kernel, dim3(32, 24), dim3(256), 0, stream, A, Wqkv, Qb, Kb, Vt);
    hipLaunchKernelGGL(attn_kernel, dim3(16, 32), dim3(256), 0, stream, Qb, Kb, Vt, AO);
    hipLaunchKernelGGL(out_kernel, dim3(64), dim3(256), 0, stream, AO, Wout, Out);
}

// Round 5
// 138.366 us; speedup vs baseline: 2.2562x; 1.0501x over previous
//
#include <hip/hip_runtime.h>
#include <hip/hip_bf16.h>
#include <math.h>

typedef __attribute__((ext_vector_type(8))) short bf16x8;
typedef __attribute__((ext_vector_type(4))) float f32x4;
typedef __attribute__((ext_vector_type(4))) unsigned u32x4;
typedef __attribute__((ext_vector_type(2))) unsigned u32x2;

union bfpack { u32x4 u; bf16x8 h; };

__device__ inline unsigned bfraw(float f) {
    union { float f; unsigned u; } x; x.f = f;
    return x.u + 0x8000u;            // round-half-up to bf16
}
__device__ inline short f2bf(float f) { return (short)(bfraw(f) >> 16); }
__device__ inline unsigned pkbf(float lo, float hi) {
    return __builtin_amdgcn_perm(bfraw(hi), bfraw(lo), 0x07060302);
}
__device__ inline float fast_exp2(float x) {
#if __has_builtin(__builtin_amdgcn_exp2f)
    return __builtin_amdgcn_exp2f(x);
#else
    return exp2f(x);
#endif
}
__device__ inline void gl_lds16(const short* g, short* l) {
    __builtin_amdgcn_global_load_lds(
        (const __attribute__((address_space(1))) unsigned*)g,
        (__attribute__((address_space(3))) unsigned*)l, 16, 0, 0);
}
#define SCQ 0.18033688011112042f     // 0.125 * log2(e), folded into Q

// ---------------------------------------------------------------------------
// Kernel 0: transpose fp32 [R][C] -> bf16 [C][R].  grid (C/64, R/64).
// ---------------------------------------------------------------------------
__global__ __launch_bounds__(256) void trans_kernel(
        const float* __restrict__ src, short* __restrict__ dst, int R, int C) {
    __shared__ float T[64][65];
    int r0 = blockIdx.y * 64, c0 = blockIdx.x * 64;
    int t = threadIdx.x;
    {
        int kr = t >> 2, ns = (t & 3) * 16;
        const float* s = src + (size_t)(r0 + kr) * C + c0 + ns;
#pragma unroll
        for (int j = 0; j < 4; ++j) {
            f32x4 v = *(const f32x4*)(s + j * 4);
#pragma unroll
            for (int e = 0; e < 4; ++e) T[kr][ns + j * 4 + e] = v[e];
        }
    }
    __syncthreads();
    {
        int n = t >> 2, ks = (t & 3) * 16;
        bfpack p0, p1;
#pragma unroll
        for (int j = 0; j < 4; ++j) {
            float a = T[ks + 2 * j][n], b = T[ks + 2 * j + 1][n];
            p0.u[j] = pkbf(a, b);
        }
#pragma unroll
        for (int j = 0; j < 4; ++j) {
            float a = T[ks + 8 + 2 * j][n], b = T[ks + 8 + 2 * j + 1][n];
            p1.u[j] = pkbf(a, b);
        }
        short* d = dst + (size_t)(c0 + n) * R + r0 + ks;
        *(bf16x8*)d = p0.h;
        *(bf16x8*)(d + 8) = p1.h;
    }
}

// ---------------------------------------------------------------------------
// Kernel 1: qkv = array(4096x256 fp32) @ Wqkv'(3072n x 256k bf16).
// 128x128 tile, BK=64, 4 iters. B via global_load_lds swizzled; A manual pack.
//   Q -> (B,H,N,64) pre-scaled SCQ; K -> (B,H,N,64); V -> (B,H,64,N).
// ---------------------------------------------------------------------------
__global__ __launch_bounds__(256) void qkv_kernel(
        const float* __restrict__ A, const short* __restrict__ Wt,
        short* __restrict__ Qb, short* __restrict__ Kb, short* __restrict__ Vt) {
    __shared__ short As[128 * 64];   // [m][k-chunk swizzled by m&7]
    __shared__ short Bs[128 * 64];   // [n][k-chunk swizzled by n&7]
    int m0 = blockIdx.x * 128;
    int n0 = blockIdx.y * 128;
    int t = threadIdx.x;
    int wave = t >> 6, lane = t & 63;
    int quad = lane >> 4, l16 = lane & 15;
    int r8 = lane >> 3, c8 = lane & 7;
    f32x4 acc[2][8] = {};
    for (int it = 0; it < 4; ++it) {
        int k0 = it * 64;
        __syncthreads();
        // ---- B staging: 4 passes of 8 rows per wave via gl_lds ----
#pragma unroll
        for (int j = 0; j < 4; ++j) {
            int row = wave * 32 + j * 8 + r8;
            int clog = c8 ^ (row & 7);
            gl_lds16(Wt + (size_t)(n0 + row) * 256 + k0 + clog * 8,
                     &Bs[(wave * 32 + j * 8) * 64]);
        }
        // ---- A staging: fp32 -> bf16 pack, swizzled b128 writes ----
        {
            int row = t >> 1, half = t & 1;
            const float* as = A + (size_t)(m0 + row) * 256 + k0 + half * 32;
#pragma unroll
            for (int cc = 0; cc < 2; ++cc) {
                f32x4 a0 = ((const f32x4*)as)[cc * 4 + 0];
                f32x4 a1 = ((const f32x4*)as)[cc * 4 + 1];
                f32x4 a2 = ((const f32x4*)as)[cc * 4 + 2];
                f32x4 a3 = ((const f32x4*)as)[cc * 4 + 3];
                bfpack v0, v1;
                v0.u[0] = pkbf(a0[0], a0[1]); v0.u[1] = pkbf(a0[2], a0[3]);
                v0.u[2] = pkbf(a1[0], a1[1]); v0.u[3] = pkbf(a1[2], a1[3]);
                v1.u[0] = pkbf(a2[0], a2[1]); v1.u[1] = pkbf(a2[2], a2[3]);
                v1.u[2] = pkbf(a3[0], a3[1]); v1.u[3] = pkbf(a3[2], a3[3]);
                int cl0 = half * 4 + cc * 2;
                *(bf16x8*)&As[row * 64 + ((cl0    ) ^ (row & 7)) * 8] = v0.h;
                *(bf16x8*)&As[row * 64 + ((cl0 + 1) ^ (row & 7)) * 8] = v1.h;
            }
        }
        __syncthreads();
        bf16x8 af[2][2];
#pragma unroll
        for (int s = 0; s < 2; ++s) {
            int m = wave * 32 + s * 16 + l16;
#pragma unroll
            for (int kh = 0; kh < 2; ++kh)
                af[s][kh] = *(const bf16x8*)&As[m * 64 + (((quad + 4 * kh)) ^ (m & 7)) * 8];
        }
#pragma unroll
        for (int c = 0; c < 8; ++c) {
            int n = c * 16 + l16;
            bf16x8 b0 = *(const bf16x8*)&Bs[n * 64 + ((quad    ) ^ (n & 7)) * 8];
            bf16x8 b1 = *(const bf16x8*)&Bs[n * 64 + ((quad + 4) ^ (n & 7)) * 8];
#pragma unroll
            for (int s = 0; s < 2; ++s) {
                acc[s][c] = __builtin_amdgcn_mfma_f32_16x16x32_bf16(af[s][0], b0, acc[s][c], 0, 0, 0);
                acc[s][c] = __builtin_amdgcn_mfma_f32_16x16x32_bf16(af[s][1], b1, acc[s][c], 0, 0, 0);
            }
        }
    }
    int sel = n0 >> 10;
    int b = m0 >> 11;
    int nb = (m0 & 2047) + wave * 32;
#pragma unroll
    for (int s = 0; s < 2; ++s) {
#pragma unroll
        for (int c = 0; c < 8; ++c) {
            int gc = n0 + c * 16 + l16;
            int h = (gc >> 6) & 15, dim = gc & 63;
            int n_base = nb + s * 16 + quad * 4;
            if (sel == 2) {
                u32x2 pk;
                pk[0] = pkbf(acc[s][c][0], acc[s][c][1]);
                pk[1] = pkbf(acc[s][c][2], acc[s][c][3]);
                *(u32x2*)&Vt[(((size_t)(b * 16 + h) * 64 + dim) << 11) + n_base] = pk;
            } else {
                short* dst = (sel == 0) ? Qb : Kb;
                float sc = (sel == 0) ? SCQ : 1.0f;
#pragma unroll
                for (int r = 0; r < 4; ++r)
                    dst[(((size_t)(b * 16 + h) * 2048 + n_base + r) << 6) + dim] =
                        f2bf(acc[s][c][r] * sc);
            }
        }
    }
}

// ---------------------------------------------------------------------------
// Kernel 2: flash attention (unchanged structure from round 4; AO layout now
// [b*2048+n][1024] so the out-projection is a plain GEMM).
// ---------------------------------------------------------------------------
__global__ __launch_bounds__(256, 2) void attn_kernel(
        const short* __restrict__ Qb, const short* __restrict__ Kb,
        const short* __restrict__ Vt, short* __restrict__ AO) {
    __shared__ short KT[2][64 * 64];
    __shared__ short VT[2][64 * 64];
    int bh = blockIdx.y, qt = blockIdx.x;
    int b = bh >> 4, h = bh & 15;
    int t = threadIdx.x, wave = t >> 6, lane = t & 63;
    int quad = lane >> 4, l16 = lane & 15;
    const short* Qp = Qb + (size_t)bh * (2048 * 64);
    const short* Kp = Kb + (size_t)bh * (2048 * 64);
    const short* Vp = Vt + (size_t)bh * (64 * 2048);
    int q0 = qt * 128 + wave * 32;

    bf16x8 qf[2][2];
#pragma unroll
    for (int sq = 0; sq < 2; ++sq) {
        const short* qp = Qp + (size_t)(q0 + sq * 16 + l16) * 64 + quad * 8;
        qf[sq][0] = *(const bf16x8*)qp;
        qf[sq][1] = *(const bf16x8*)(qp + 32);
    }
    int r8 = lane >> 3, p8 = lane & 7;
    int kr0 = wave * 16 + r8, kr1 = kr0 + 8;
    int swz0 = (kr0 & 3) | (((kr0 >> 3) & 1) << 2);
    int swz1 = (kr1 & 3) | (((kr1 >> 3) & 1) << 2);
    const short* gk0 = Kp + kr0 * 64 + (p8 ^ swz0) * 8;
    const short* gk1 = Kp + kr1 * 64 + (p8 ^ swz1) * 8;
    const short* gv0 = Vp + kr0 * 2048 + (p8 ^ (kr0 & 7)) * 8;
    const short* gv1 = Vp + kr1 * 2048 + (p8 ^ (kr1 & 7)) * 8;
    int ldsk0 = wave * 1024, ldsk1 = wave * 1024 + 512;
    int swzk = (l16 & 3) | (((l16 >> 2) & 1) << 2);
    int krd = ((l16 >> 2) * 8 + (l16 & 3)) * 64;
    int koff0 = krd + ((quad ^ swzk) * 8);
    int koff1 = krd + (((quad + 4) ^ swzk) * 8);
    int voff0 = l16 * 64 + ((quad ^ (l16 & 7)) * 8);
    int voff1 = l16 * 64 + (((quad + 4) ^ (l16 & 7)) * 8);

    f32x4 o[2][4] = {};
    f32x4 ol[2] = {};
    bf16x8 ones = {(short)0x3F80, (short)0x3F80, (short)0x3F80, (short)0x3F80,
                   (short)0x3F80, (short)0x3F80, (short)0x3F80, (short)0x3F80};

    gl_lds16(gk0, &KT[0][ldsk0]);
    gl_lds16(gk1, &KT[0][ldsk1]);
    gl_lds16(gv0, &VT[0][ldsk0]);
    gl_lds16(gv1, &VT[0][ldsk1]);

    for (int kt = 0; kt < 32; ++kt) {
        __syncthreads();
        if (kt + 1 < 32) {
            int buf = (kt + 1) & 1;
            gl_lds16(gk0 + (size_t)(kt + 1) * 4096, &KT[buf][ldsk0]);
            gl_lds16(gk1 + (size_t)(kt + 1) * 4096, &KT[buf][ldsk1]);
            gl_lds16(gv0 + (kt + 1) * 64, &VT[buf][ldsk0]);
            gl_lds16(gv1 + (kt + 1) * 64, &VT[buf][ldsk1]);
        }
        const short* kb = &KT[kt & 1][0];
        const short* vb = &VT[kt & 1][0];
        bf16x8 kc[8], vc[8];
#pragma unroll
        for (int hh = 0; hh < 2; ++hh)
#pragma unroll
            for (int ab = 0; ab < 2; ++ab) {
                kc[(hh * 2 + ab) * 2 + 0] = *(const bf16x8*)&kb[koff0 + ab * 256 + hh * 2048];
                kc[(hh * 2 + ab) * 2 + 1] = *(const bf16x8*)&kb[koff1 + ab * 256 + hh * 2048];
            }
#pragma unroll
        for (int hh = 0; hh < 2; ++hh)
#pragma unroll
            for (int dt = 0; dt < 4; ++dt)
                vc[hh * 4 + dt] = *(const bf16x8*)&vb[(hh ? voff1 : voff0) + dt * 1024];

#pragma unroll
        for (int sq = 0; sq < 2; ++sq) {
            f32x4 s[4];
#pragma unroll
            for (int i = 0; i < 4; ++i) {
                f32x4 z = {};
                z = __builtin_amdgcn_mfma_f32_16x16x32_bf16(kc[2 * i], qf[sq][0], z, 0, 0, 0);
                z = __builtin_amdgcn_mfma_f32_16x16x32_bf16(kc[2 * i + 1], qf[sq][1], z, 0, 0, 0);
                s[i] = z;
            }
            bfpack pa0, pa1;
#pragma unroll
            for (int ab = 0; ab < 2; ++ab) {
                float p0 = fast_exp2(s[ab][0]),      p1 = fast_exp2(s[ab][1]);
                float p2 = fast_exp2(s[ab][2]),      p3 = fast_exp2(s[ab][3]);
                float q0e = fast_exp2(s[2 + ab][0]), q1e = fast_exp2(s[2 + ab][1]);
                float q2e = fast_exp2(s[2 + ab][2]), q3e = fast_exp2(s[2 + ab][3]);
                pa0.u[ab * 2 + 0] = pkbf(p0, p1);
                pa0.u[ab * 2 + 1] = pkbf(p2, p3);
                pa1.u[ab * 2 + 0] = pkbf(q0e, q1e);
                pa1.u[ab * 2 + 1] = pkbf(q2e, q3e);
            }
            ol[sq] = __builtin_amdgcn_mfma_f32_16x16x32_bf16(pa0.h, ones, ol[sq], 0, 0, 0);
            ol[sq] = __builtin_amdgcn_mfma_f32_16x16x32_bf16(pa1.h, ones, ol[sq], 0, 0, 0);
#pragma unroll
            for (int dt = 0; dt < 4; ++dt) {
                o[sq][dt] = __builtin_amdgcn_mfma_f32_16x16x32_bf16(pa0.h, vc[dt],
                                                                    o[sq][dt], 0, 0, 0);
                o[sq][dt] = __builtin_amdgcn_mfma_f32_16x16x32_bf16(pa1.h, vc[4 + dt],
                                                                    o[sq][dt], 0, 0, 0);
            }
        }
    }
#pragma unroll
    for (int sq = 0; sq < 2; ++sq) {
        f32x4 inv;
#pragma unroll
        for (int r = 0; r < 4; ++r) inv[r] = 1.0f / ol[sq][r];
#pragma unroll
        for (int dt = 0; dt < 4; ++dt)
#pragma unroll
            for (int r = 0; r < 4; ++r) {
                int qrow = q0 + sq * 16 + quad * 4 + r;
                AO[((size_t)(b * 2048 + qrow)) * 1024 + h * 64 + dt * 16 + l16] =
                    f2bf(o[sq][dt][r] * inv[r]);
            }
    }
}

// ---------------------------------------------------------------------------
// Kernel 3: out = AO(4096x1024 bf16) @ Wout'(64n x 1024k bf16) -> fp32.
// M-tile 64, BK=64, 16 iters, both operands via swizzled global_load_lds.
// ---------------------------------------------------------------------------
__global__ __launch_bounds__(256) void out_kernel(
        const short* __restrict__ AO, const short* __restrict__ Wo,
        float* __restrict__ Out) {
    __shared__ short As[64 * 64];
    __shared__ short Bs[64 * 64];
    int m0 = blockIdx.x * 64;
    int t = threadIdx.x, wave = t >> 6, lane = t & 63;
    int quad = lane >> 4, l16 = lane & 15;
    int r8 = lane >> 3, c8 = lane & 7;
    f32x4 acc[4] = {};
    for (int it = 0; it < 16; ++it) {
        int k0 = it * 64;
        __syncthreads();
#pragma unroll
        for (int j = 0; j < 2; ++j) {
            int row = wave * 16 + j * 8 + r8;
            int clog = c8 ^ (row & 7);
            gl_lds16(AO + (size_t)(m0 + row) * 1024 + k0 + clog * 8,
                     &As[(wave * 16 + j * 8) * 64]);
            gl_lds16(Wo + (size_t)row * 1024 + k0 + clog * 8,
                     &Bs[(wave * 16 + j * 8) * 64]);
        }
        __syncthreads();
        int m = wave * 16 + l16;
        bf16x8 a0 = *(const bf16x8*)&As[m * 64 + ((quad    ) ^ (m & 7)) * 8];
        bf16x8 a1 = *(const bf16x8*)&As[m * 64 + ((quad + 4) ^ (m & 7)) * 8];
#pragma unroll
        for (int c = 0; c < 4; ++c) {
            int n = c * 16 + l16;
            bf16x8 b0 = *(const bf16x8*)&Bs[n * 64 + ((quad    ) ^ (n & 7)) * 8];
            bf16x8 b1 = *(const bf16x8*)&Bs[n * 64 + ((quad + 4) ^ (n & 7)) * 8];
            acc[c] = __builtin_amdgcn_mfma_f32_16x16x32_bf16(a0, b0, acc[c], 0, 0, 0);
            acc[c] = __builtin_amdgcn_mfma_f32_16x16x32_bf16(a1, b1, acc[c], 0, 0, 0);
        }
    }
#pragma unroll
    for (int c = 0; c < 4; ++c)
#pragma unroll
        for (int r = 0; r < 4; ++r) {
            int gm = m0 + wave * 16 + quad * 4 + r;
            Out[((size_t)gm << 6) + c * 16 + l16] = acc[c][r];
        }
}

// ---------------------------------------------------------------------------
extern "C" void kernel_launch(void* const* d_in, const int* in_sizes, int n_in,
                              void* d_out, int out_size, void* d_ws, size_t ws_size,
                              hipStream_t stream) {
    const float* A    = (const float*)d_in[0];   // (2,2048,256)
    const float* Wqkv = (const float*)d_in[1];   // (256,3072)
    const float* Wout = (const float*)d_in[2];   // (1024,64)
    float* Out = (float*)d_out;                  // (2,2048,64) fp32

    short* ws = (short*)d_ws;
    short* Wq = ws;                      // (3072,256) bf16
    short* Wo = ws + 786432;             // (64,1024) bf16
    short* Qb = ws + 851968;             // (B,H,N,64)
    short* Kb = ws + 5046272;            // (B,H,N,64)
    short* Vt = ws + 9240576;            // (B,H,64,N)
    short* AO = ws + 13434880;           // (4096,1024)

    hipLaunchKernelGGL(trans_kernel, dim3(48, 4), dim3(256), 0, stream, Wqkv, Wq, 256, 3072);
    hipLaunchKernelGGL(trans_kernel, dim3(1, 16), dim3(256), 0, stream, Wout, Wo, 1024, 64);
    hipLaunchKernelGGL(qkv_kernel, dim3(32, 24), dim3(256), 0, stream, A, Wq, Qb, Kb, Vt);
    hipLaunchKernelGGL(attn_kernel, dim3(16, 32), dim3(256), 0, stream, Qb, Kb, Vt, AO);
    hipLaunchKernelGGL(out_kernel, dim3(64), dim3(256), 0, stream, AO, Wo, Out);
}

// Round 6
// 137.695 us; speedup vs baseline: 2.2672x; 1.0049x over previous
//
#include <hip/hip_runtime.h>
#include <hip/hip_bf16.h>
#include <math.h>

typedef __attribute__((ext_vector_type(8))) short bf16x8;
typedef __attribute__((ext_vector_type(4))) float f32x4;
typedef __attribute__((ext_vector_type(4))) unsigned u32x4;
typedef __attribute__((ext_vector_type(2))) unsigned u32x2;

union bfpack { u32x4 u; bf16x8 h; };

__device__ inline unsigned bfraw(float f) {
    union { float f; unsigned u; } x; x.f = f;
    return x.u + 0x8000u;            // round-half-up to bf16
}
__device__ inline short f2bf(float f) { return (short)(bfraw(f) >> 16); }
__device__ inline unsigned pkbf(float lo, float hi) {
    return __builtin_amdgcn_perm(bfraw(hi), bfraw(lo), 0x07060302);
}
__device__ inline float fast_exp2(float x) {
#if __has_builtin(__builtin_amdgcn_exp2f)
    return __builtin_amdgcn_exp2f(x);
#else
    return exp2f(x);
#endif
}
__device__ inline void gl_lds16(const short* g, short* l) {
    __builtin_amdgcn_global_load_lds(
        (const __attribute__((address_space(1))) unsigned*)g,
        (__attribute__((address_space(3))) unsigned*)l, 16, 0, 0);
}
#define SCQ 0.18033688011112042f     // 0.125 * log2(e), folded into Q

// ---------------------------------------------------------------------------
// Kernel Z: zero the fp32 output (attn accumulates into it with atomics).
// ---------------------------------------------------------------------------
__global__ __launch_bounds__(256) void zero_kernel(float* __restrict__ p) {
    int i = blockIdx.x * 256 + threadIdx.x;
    f32x4 z = {};
    ((f32x4*)p)[i] = z;
}

// ---------------------------------------------------------------------------
// Kernel 0: transpose fp32 [R][C] -> bf16 [C][R].  grid (C/64, R/64).
// ---------------------------------------------------------------------------
__global__ __launch_bounds__(256) void trans_kernel(
        const float* __restrict__ src, short* __restrict__ dst, int R, int C) {
    __shared__ float T[64][65];
    int r0 = blockIdx.y * 64, c0 = blockIdx.x * 64;
    int t = threadIdx.x;
    {
        int kr = t >> 2, ns = (t & 3) * 16;
        const float* s = src + (size_t)(r0 + kr) * C + c0 + ns;
#pragma unroll
        for (int j = 0; j < 4; ++j) {
            f32x4 v = *(const f32x4*)(s + j * 4);
#pragma unroll
            for (int e = 0; e < 4; ++e) T[kr][ns + j * 4 + e] = v[e];
        }
    }
    __syncthreads();
    {
        int n = t >> 2, ks = (t & 3) * 16;
        bfpack p0, p1;
#pragma unroll
        for (int j = 0; j < 4; ++j) p0.u[j] = pkbf(T[ks + 2 * j][n], T[ks + 2 * j + 1][n]);
#pragma unroll
        for (int j = 0; j < 4; ++j) p1.u[j] = pkbf(T[ks + 8 + 2 * j][n], T[ks + 9 + 2 * j][n]);
        short* d = dst + (size_t)(c0 + n) * R + r0 + ks;
        *(bf16x8*)d = p0.h;
        *(bf16x8*)(d + 8) = p1.h;
    }
}

// ---------------------------------------------------------------------------
// Kernel 1: qkv = array(4096x256 fp32) @ Wqkv'(3072n x 256k bf16).
// 128x128 tile, BK=64, 4 iters. (unchanged from round 5)
// ---------------------------------------------------------------------------
__global__ __launch_bounds__(256) void qkv_kernel(
        const float* __restrict__ A, const short* __restrict__ Wt,
        short* __restrict__ Qb, short* __restrict__ Kb, short* __restrict__ Vt) {
    __shared__ short As[128 * 64];
    __shared__ short Bs[128 * 64];
    int m0 = blockIdx.x * 128;
    int n0 = blockIdx.y * 128;
    int t = threadIdx.x;
    int wave = t >> 6, lane = t & 63;
    int quad = lane >> 4, l16 = lane & 15;
    int r8 = lane >> 3, c8 = lane & 7;
    f32x4 acc[2][8] = {};
    for (int it = 0; it < 4; ++it) {
        int k0 = it * 64;
        __syncthreads();
#pragma unroll
        for (int j = 0; j < 4; ++j) {
            int row = wave * 32 + j * 8 + r8;
            int clog = c8 ^ (row & 7);
            gl_lds16(Wt + (size_t)(n0 + row) * 256 + k0 + clog * 8,
                     &Bs[(wave * 32 + j * 8) * 64]);
        }
        {
            int row = t >> 1, half = t & 1;
            const float* as = A + (size_t)(m0 + row) * 256 + k0 + half * 32;
#pragma unroll
            for (int cc = 0; cc < 2; ++cc) {
                f32x4 a0 = ((const f32x4*)as)[cc * 4 + 0];
                f32x4 a1 = ((const f32x4*)as)[cc * 4 + 1];
                f32x4 a2 = ((const f32x4*)as)[cc * 4 + 2];
                f32x4 a3 = ((const f32x4*)as)[cc * 4 + 3];
                bfpack v0, v1;
                v0.u[0] = pkbf(a0[0], a0[1]); v0.u[1] = pkbf(a0[2], a0[3]);
                v0.u[2] = pkbf(a1[0], a1[1]); v0.u[3] = pkbf(a1[2], a1[3]);
                v1.u[0] = pkbf(a2[0], a2[1]); v1.u[1] = pkbf(a2[2], a2[3]);
                v1.u[2] = pkbf(a3[0], a3[1]); v1.u[3] = pkbf(a3[2], a3[3]);
                int cl0 = half * 4 + cc * 2;
                *(bf16x8*)&As[row * 64 + ((cl0    ) ^ (row & 7)) * 8] = v0.h;
                *(bf16x8*)&As[row * 64 + ((cl0 + 1) ^ (row & 7)) * 8] = v1.h;
            }
        }
        __syncthreads();
        bf16x8 af[2][2];
#pragma unroll
        for (int s = 0; s < 2; ++s) {
            int m = wave * 32 + s * 16 + l16;
#pragma unroll
            for (int kh = 0; kh < 2; ++kh)
                af[s][kh] = *(const bf16x8*)&As[m * 64 + (((quad + 4 * kh)) ^ (m & 7)) * 8];
        }
#pragma unroll
        for (int c = 0; c < 8; ++c) {
            int n = c * 16 + l16;
            bf16x8 b0 = *(const bf16x8*)&Bs[n * 64 + ((quad    ) ^ (n & 7)) * 8];
            bf16x8 b1 = *(const bf16x8*)&Bs[n * 64 + ((quad + 4) ^ (n & 7)) * 8];
#pragma unroll
            for (int s = 0; s < 2; ++s) {
                acc[s][c] = __builtin_amdgcn_mfma_f32_16x16x32_bf16(af[s][0], b0, acc[s][c], 0, 0, 0);
                acc[s][c] = __builtin_amdgcn_mfma_f32_16x16x32_bf16(af[s][1], b1, acc[s][c], 0, 0, 0);
            }
        }
    }
    int sel = n0 >> 10;
    int b = m0 >> 11;
    int nb = (m0 & 2047) + wave * 32;
#pragma unroll
    for (int s = 0; s < 2; ++s) {
#pragma unroll
        for (int c = 0; c < 8; ++c) {
            int gc = n0 + c * 16 + l16;
            int h = (gc >> 6) & 15, dim = gc & 63;
            int n_base = nb + s * 16 + quad * 4;
            if (sel == 2) {
                u32x2 pk;
                pk[0] = pkbf(acc[s][c][0], acc[s][c][1]);
                pk[1] = pkbf(acc[s][c][2], acc[s][c][3]);
                *(u32x2*)&Vt[(((size_t)(b * 16 + h) * 64 + dim) << 11) + n_base] = pk;
            } else {
                short* dst = (sel == 0) ? Qb : Kb;
                float sc = (sel == 0) ? SCQ : 1.0f;
#pragma unroll
                for (int r = 0; r < 4; ++r)
                    dst[(((size_t)(b * 16 + h) * 2048 + n_base + r) << 6) + dim] =
                        f2bf(acc[s][c][r] * sc);
            }
        }
    }
}

// ---------------------------------------------------------------------------
// Kernel 2: flash attention + FUSED out-projection.
// Wave owns 16 queries; grid (32,32) = 1024 blocks -> 4 blocks/CU.
// Epilogue: R = (O/l) @ Wout'[.,h*64:+64]^T via one more MFMA pass, fp32
// atomicAdd into Out (summing over heads).
// ---------------------------------------------------------------------------
__global__ __launch_bounds__(256, 4) void attn_kernel(
        const short* __restrict__ Qb, const short* __restrict__ Kb,
        const short* __restrict__ Vt, const short* __restrict__ Wo,
        float* __restrict__ Out) {
    __shared__ short KT[2][64 * 64];
    __shared__ short VT[2][64 * 64];
    int bh = blockIdx.y, qt = blockIdx.x;
    int b = bh >> 4, h = bh & 15;
    int t = threadIdx.x, wave = t >> 6, lane = t & 63;
    int quad = lane >> 4, l16 = lane & 15;
    const short* Qp = Qb + (size_t)bh * (2048 * 64);
    const short* Kp = Kb + (size_t)bh * (2048 * 64);
    const short* Vp = Vt + (size_t)bh * (64 * 2048);
    int q0 = qt * 64 + wave * 16;

    bf16x8 qf0, qf1;
    {
        const short* qp = Qp + (size_t)(q0 + l16) * 64 + quad * 8;
        qf0 = *(const bf16x8*)qp;
        qf1 = *(const bf16x8*)(qp + 32);
    }
    int r8 = lane >> 3, p8 = lane & 7;
    int kr0 = wave * 16 + r8, kr1 = kr0 + 8;
    int swz0 = (kr0 & 3) | (((kr0 >> 3) & 1) << 2);
    int swz1 = (kr1 & 3) | (((kr1 >> 3) & 1) << 2);
    const short* gk0 = Kp + kr0 * 64 + (p8 ^ swz0) * 8;
    const short* gk1 = Kp + kr1 * 64 + (p8 ^ swz1) * 8;
    const short* gv0 = Vp + kr0 * 2048 + (p8 ^ (kr0 & 7)) * 8;
    const short* gv1 = Vp + kr1 * 2048 + (p8 ^ (kr1 & 7)) * 8;
    int ldsk0 = wave * 1024, ldsk1 = wave * 1024 + 512;
    int swzk = (l16 & 3) | (((l16 >> 2) & 1) << 2);
    int krd = ((l16 >> 2) * 8 + (l16 & 3)) * 64;
    int koff0 = krd + ((quad ^ swzk) * 8);
    int koff1 = krd + (((quad + 4) ^ swzk) * 8);
    int voff0 = l16 * 64 + ((quad ^ (l16 & 7)) * 8);
    int voff1 = l16 * 64 + (((quad + 4) ^ (l16 & 7)) * 8);

    f32x4 o[4] = {};
    f32x4 ol = {};
    bf16x8 ones = {(short)0x3F80, (short)0x3F80, (short)0x3F80, (short)0x3F80,
                   (short)0x3F80, (short)0x3F80, (short)0x3F80, (short)0x3F80};

    gl_lds16(gk0, &KT[0][ldsk0]);
    gl_lds16(gk1, &KT[0][ldsk1]);
    gl_lds16(gv0, &VT[0][ldsk0]);
    gl_lds16(gv1, &VT[0][ldsk1]);

    for (int kt = 0; kt < 32; ++kt) {
        __syncthreads();
        if (kt + 1 < 32) {
            int buf = (kt + 1) & 1;
            gl_lds16(gk0 + (size_t)(kt + 1) * 4096, &KT[buf][ldsk0]);
            gl_lds16(gk1 + (size_t)(kt + 1) * 4096, &KT[buf][ldsk1]);
            gl_lds16(gv0 + (kt + 1) * 64, &VT[buf][ldsk0]);
            gl_lds16(gv1 + (kt + 1) * 64, &VT[buf][ldsk1]);
        }
        const short* kb = &KT[kt & 1][0];
        const short* vb = &VT[kt & 1][0];
        bf16x8 kc[8], vc[8];
#pragma unroll
        for (int hh = 0; hh < 2; ++hh)
#pragma unroll
            for (int ab = 0; ab < 2; ++ab) {
                kc[(hh * 2 + ab) * 2 + 0] = *(const bf16x8*)&kb[koff0 + ab * 256 + hh * 2048];
                kc[(hh * 2 + ab) * 2 + 1] = *(const bf16x8*)&kb[koff1 + ab * 256 + hh * 2048];
            }
#pragma unroll
        for (int hh = 0; hh < 2; ++hh)
#pragma unroll
            for (int dt = 0; dt < 4; ++dt)
                vc[hh * 4 + dt] = *(const bf16x8*)&vb[(hh ? voff1 : voff0) + dt * 1024];

        f32x4 s[4];
#pragma unroll
        for (int i = 0; i < 4; ++i) {
            f32x4 z = {};
            z = __builtin_amdgcn_mfma_f32_16x16x32_bf16(kc[2 * i], qf0, z, 0, 0, 0);
            z = __builtin_amdgcn_mfma_f32_16x16x32_bf16(kc[2 * i + 1], qf1, z, 0, 0, 0);
            s[i] = z;
        }
        bfpack pa0, pa1;
#pragma unroll
        for (int ab = 0; ab < 2; ++ab) {
            float p0 = fast_exp2(s[ab][0]),      p1 = fast_exp2(s[ab][1]);
            float p2 = fast_exp2(s[ab][2]),      p3 = fast_exp2(s[ab][3]);
            float q0e = fast_exp2(s[2 + ab][0]), q1e = fast_exp2(s[2 + ab][1]);
            float q2e = fast_exp2(s[2 + ab][2]), q3e = fast_exp2(s[2 + ab][3]);
            pa0.u[ab * 2 + 0] = pkbf(p0, p1);
            pa0.u[ab * 2 + 1] = pkbf(p2, p3);
            pa1.u[ab * 2 + 0] = pkbf(q0e, q1e);
            pa1.u[ab * 2 + 1] = pkbf(q2e, q3e);
        }
        ol = __builtin_amdgcn_mfma_f32_16x16x32_bf16(pa0.h, ones, ol, 0, 0, 0);
        ol = __builtin_amdgcn_mfma_f32_16x16x32_bf16(pa1.h, ones, ol, 0, 0, 0);
#pragma unroll
        for (int dt = 0; dt < 4; ++dt) {
            o[dt] = __builtin_amdgcn_mfma_f32_16x16x32_bf16(pa0.h, vc[dt],     o[dt], 0, 0, 0);
            o[dt] = __builtin_amdgcn_mfma_f32_16x16x32_bf16(pa1.h, vc[4 + dt], o[dt], 0, 0, 0);
        }
    }

    // ---- fused out-projection epilogue ----
    // Stage Ws (head-h 64x64 Wout' slice, [n][k]) into KT[0]; pack scaled O
    // (A-frag layout) into VT[0]. Both buf-0 regions are dead after iter 31.
    short* WsL = &KT[0][0];
    short* myO = &VT[0][wave * 1024];
#pragma unroll
    for (int j = 0; j < 2; ++j) {
        int n = wave * 16 + j * 8 + r8;
        gl_lds16(Wo + (size_t)n * 1024 + h * 64 + ((p8 ^ (n & 7)) * 8),
                 &WsL[(wave * 16 + j * 8) * 64]);
    }
    f32x4 inv;
#pragma unroll
    for (int r = 0; r < 4; ++r) inv[r] = 1.0f / ol[r];
#pragma unroll
    for (int dt = 0; dt < 4; ++dt) {
#pragma unroll
        for (int r = 0; r < 4; ++r) {
            int q = quad * 4 + r;
            int col = dt * 16 + l16;
            int c = col >> 3;
            myO[q * 64 + ((c ^ (q & 7)) * 8) + (col & 7)] = f2bf(o[dt][r] * inv[r]);
        }
    }
    __syncthreads();
    bf16x8 a0 = *(const bf16x8*)&myO[l16 * 64 + ((quad       ^ (l16 & 7)) * 8)];
    bf16x8 a1 = *(const bf16x8*)&myO[l16 * 64 + (((quad + 4) ^ (l16 & 7)) * 8)];
    float* OutRow = Out + ((size_t)(b * 2048 + q0)) * 64;
#pragma unroll
    for (int c = 0; c < 4; ++c) {
        int n = c * 16 + l16;
        bf16x8 b0 = *(const bf16x8*)&WsL[n * 64 + ((quad       ^ (n & 7)) * 8)];
        bf16x8 b1 = *(const bf16x8*)&WsL[n * 64 + (((quad + 4) ^ (n & 7)) * 8)];
        f32x4 rg = {};
        rg = __builtin_amdgcn_mfma_f32_16x16x32_bf16(a0, b0, rg, 0, 0, 0);
        rg = __builtin_amdgcn_mfma_f32_16x16x32_bf16(a1, b1, rg, 0, 0, 0);
#pragma unroll
        for (int r = 0; r < 4; ++r)
            atomicAdd(&OutRow[(quad * 4 + r) * 64 + n], rg[r]);
    }
}

// ---------------------------------------------------------------------------
extern "C" void kernel_launch(void* const* d_in, const int* in_sizes, int n_in,
                              void* d_out, int out_size, void* d_ws, size_t ws_size,
                              hipStream_t stream) {
    const float* A    = (const float*)d_in[0];   // (2,2048,256)
    const float* Wqkv = (const float*)d_in[1];   // (256,3072)
    const float* Wout = (const float*)d_in[2];   // (1024,64)
    float* Out = (float*)d_out;                  // (2,2048,64) fp32

    short* ws = (short*)d_ws;
    short* Wq = ws;                      // (3072,256) bf16
    short* Wo = ws + 786432;             // (64,1024) bf16
    short* Qb = ws + 851968;             // (B,H,N,64)
    short* Kb = ws + 5046272;            // (B,H,N,64)
    short* Vt = ws + 9240576;            // (B,H,64,N)

    hipLaunchKernelGGL(zero_kernel, dim3(256), dim3(256), 0, stream, Out);
    hipLaunchKernelGGL(trans_kernel, dim3(48, 4), dim3(256), 0, stream, Wqkv, Wq, 256, 3072);
    hipLaunchKernelGGL(trans_kernel, dim3(1, 16), dim3(256), 0, stream, Wout, Wo, 1024, 64);
    hipLaunchKernelGGL(qkv_kernel, dim3(32, 24), dim3(256), 0, stream, A, Wq, Qb, Kb, Vt);
    hipLaunchKernelGGL(attn_kernel, dim3(32, 32), dim3(256), 0, stream, Qb, Kb, Vt, Wo, Out);
}

// Round 10
// 131.954 us; speedup vs baseline: 2.3658x; 1.0435x over previous
//
#include <hip/hip_runtime.h>
#include <hip/hip_bf16.h>
#include <math.h>

typedef __attribute__((ext_vector_type(8))) short bf16x8;
typedef __attribute__((ext_vector_type(4))) float f32x4;
typedef __attribute__((ext_vector_type(4))) unsigned u32x4;
typedef __attribute__((ext_vector_type(2))) unsigned u32x2;

union bfpack { u32x4 u; bf16x8 h; };

__device__ inline unsigned bfraw(float f) {
    union { float f; unsigned u; } x; x.f = f;
    return x.u + 0x8000u;            // round-half-up to bf16
}
__device__ inline short f2bf(float f) { return (short)(bfraw(f) >> 16); }
__device__ inline unsigned pkbf(float lo, float hi) {
    return __builtin_amdgcn_perm(bfraw(hi), bfraw(lo), 0x07060302);
}
__device__ inline float fast_exp2(float x) {
#if __has_builtin(__builtin_amdgcn_exp2f)
    return __builtin_amdgcn_exp2f(x);
#else
    return exp2f(x);
#endif
}
__device__ inline void gl_lds16(const short* g, short* l) {
    __builtin_amdgcn_global_load_lds(
        (const __attribute__((address_space(1))) unsigned*)g,
        (__attribute__((address_space(3))) unsigned*)l, 16, 0, 0);
}
#define SCQ 0.18033688011112042f     // 0.125 * log2(e), folded into Q

// ---------------------------------------------------------------------------
// Kernel 0 (prep): 256 blocks. Zero Out (all blocks) + weight transposes:
//   blk 0..191 : Wqkv (256x3072 fp32) -> Wq (3072x256 bf16)
//   blk 192..207: Wout (1024x64 fp32) -> Wo (64x1024 bf16)
// ---------------------------------------------------------------------------
__global__ __launch_bounds__(256) void prep_kernel(
        const float* __restrict__ Wqkv, const float* __restrict__ Wout,
        short* __restrict__ Wq, short* __restrict__ Wo,
        float* __restrict__ Out) {
    __shared__ float T[64 * 65];
    int blk = blockIdx.x;
    int t = threadIdx.x;
    {
        f32x4 z = {};
        *(f32x4*)&Out[(size_t)blk * 1024 + t * 4] = z;
    }
    if (blk < 208) {
        const float* src; short* dst; int R, C, c0, r0;
        if (blk < 192) { src = Wqkv; dst = Wq; R = 256; C = 3072;
                         c0 = (blk % 48) * 64; r0 = (blk / 48) * 64; }
        else           { src = Wout; dst = Wo; R = 1024; C = 64;
                         c0 = 0; r0 = (blk - 192) * 64; }
        {
            int kr = t >> 2, ns = (t & 3) * 16;
            const float* s = src + (size_t)(r0 + kr) * C + c0 + ns;
#pragma unroll
            for (int j = 0; j < 4; ++j) {
                f32x4 v = *(const f32x4*)(s + j * 4);
#pragma unroll
                for (int e = 0; e < 4; ++e) T[kr * 65 + ns + j * 4 + e] = v[e];
            }
        }
        __syncthreads();
        {
            int n = t >> 2, ks = (t & 3) * 16;
            bfpack p0, p1;
#pragma unroll
            for (int j = 0; j < 4; ++j)
                p0.u[j] = pkbf(T[(ks + 2 * j) * 65 + n], T[(ks + 2 * j + 1) * 65 + n]);
#pragma unroll
            for (int j = 0; j < 4; ++j)
                p1.u[j] = pkbf(T[(ks + 8 + 2 * j) * 65 + n], T[(ks + 9 + 2 * j) * 65 + n]);
            short* d = dst + (size_t)(c0 + n) * R + r0 + ks;
            *(bf16x8*)d = p0.h;
            *(bf16x8*)(d + 8) = p1.h;
        }
    }
}

// ---------------------------------------------------------------------------
// Kernel 1: qkv = array(4096x256 fp32) @ Wq(3072n x 256k bf16).
// ROUND-5 VERBATIM (known good).
// ---------------------------------------------------------------------------
__global__ __launch_bounds__(256) void qkv_kernel(
        const float* __restrict__ A, const short* __restrict__ Wt,
        short* __restrict__ Qb, short* __restrict__ Kb, short* __restrict__ Vt) {
    __shared__ short As[128 * 64];   // [m][k-chunk ^ (m&7)]
    __shared__ short Bs[128 * 64];   // [n][k-chunk ^ (n&7)]
    int m0 = blockIdx.x * 128;
    int n0 = blockIdx.y * 128;
    int t = threadIdx.x;
    int wave = t >> 6, lane = t & 63;
    int quad = lane >> 4, l16 = lane & 15;
    int r8 = lane >> 3, c8 = lane & 7;
    f32x4 acc[2][8] = {};
    for (int it = 0; it < 4; ++it) {
        int k0 = it * 64;
        __syncthreads();
#pragma unroll
        for (int j = 0; j < 4; ++j) {
            int row = wave * 32 + j * 8 + r8;
            int clog = c8 ^ (row & 7);
            gl_lds16(Wt + (size_t)(n0 + row) * 256 + k0 + clog * 8,
                     &Bs[(wave * 32 + j * 8) * 64]);
        }
        {
            int row = t >> 1, half = t & 1;
            const float* as = A + (size_t)(m0 + row) * 256 + k0 + half * 32;
#pragma unroll
            for (int cc = 0; cc < 2; ++cc) {
                f32x4 a0 = ((const f32x4*)as)[cc * 4 + 0];
                f32x4 a1 = ((const f32x4*)as)[cc * 4 + 1];
                f32x4 a2 = ((const f32x4*)as)[cc * 4 + 2];
                f32x4 a3 = ((const f32x4*)as)[cc * 4 + 3];
                bfpack v0, v1;
                v0.u[0] = pkbf(a0[0], a0[1]); v0.u[1] = pkbf(a0[2], a0[3]);
                v0.u[2] = pkbf(a1[0], a1[1]); v0.u[3] = pkbf(a1[2], a1[3]);
                v1.u[0] = pkbf(a2[0], a2[1]); v1.u[1] = pkbf(a2[2], a2[3]);
                v1.u[2] = pkbf(a3[0], a3[1]); v1.u[3] = pkbf(a3[2], a3[3]);
                int cl0 = half * 4 + cc * 2;
                *(bf16x8*)&As[row * 64 + ((cl0    ) ^ (row & 7)) * 8] = v0.h;
                *(bf16x8*)&As[row * 64 + ((cl0 + 1) ^ (row & 7)) * 8] = v1.h;
            }
        }
        __syncthreads();
        bf16x8 af[2][2];
#pragma unroll
        for (int s = 0; s < 2; ++s) {
            int m = wave * 32 + s * 16 + l16;
#pragma unroll
            for (int kh = 0; kh < 2; ++kh)
                af[s][kh] = *(const bf16x8*)&As[m * 64 + ((quad + 4 * kh) ^ (m & 7)) * 8];
        }
#pragma unroll
        for (int c = 0; c < 8; ++c) {
            int n = c * 16 + l16;
            bf16x8 b0 = *(const bf16x8*)&Bs[n * 64 + ((quad    ) ^ (n & 7)) * 8];
            bf16x8 b1 = *(const bf16x8*)&Bs[n * 64 + ((quad + 4) ^ (n & 7)) * 8];
#pragma unroll
            for (int s = 0; s < 2; ++s) {
                acc[s][c] = __builtin_amdgcn_mfma_f32_16x16x32_bf16(af[s][0], b0, acc[s][c], 0, 0, 0);
                acc[s][c] = __builtin_amdgcn_mfma_f32_16x16x32_bf16(af[s][1], b1, acc[s][c], 0, 0, 0);
            }
        }
    }
    int sel = n0 >> 10;
    int b = m0 >> 11;
    int nb = (m0 & 2047) + wave * 32;
#pragma unroll
    for (int s = 0; s < 2; ++s) {
#pragma unroll
        for (int c = 0; c < 8; ++c) {
            int gc = n0 + c * 16 + l16;
            int h = (gc >> 6) & 15, dim = gc & 63;
            int n_base = nb + s * 16 + quad * 4;
            if (sel == 2) {
                u32x2 pk;
                pk[0] = pkbf(acc[s][c][0], acc[s][c][1]);
                pk[1] = pkbf(acc[s][c][2], acc[s][c][3]);
                *(u32x2*)&Vt[(((size_t)(b * 16 + h) * 64 + dim) << 11) + n_base] = pk;
            } else {
                short* dst = (sel == 0) ? Qb : Kb;
                float sc = (sel == 0) ? SCQ : 1.0f;
#pragma unroll
                for (int r = 0; r < 4; ++r)
                    dst[(((size_t)(b * 16 + h) * 2048 + n_base + r) << 6) + dim] =
                        f2bf(acc[s][c][r] * sc);
            }
        }
    }
}

// ---------------------------------------------------------------------------
// Kernel 2: flash attention + fused out-projection — ROUND-6 VERBATIM
// (known good): 16q/wave, grid (32,32), Ws staged after loop into KT[0],
// myO in VT[0], barrier before re-read, atomicAdd into Out.
// ---------------------------------------------------------------------------
__global__ __launch_bounds__(256, 4) void attn_kernel(
        const short* __restrict__ Qb, const short* __restrict__ Kb,
        const short* __restrict__ Vt, const short* __restrict__ Wo,
        float* __restrict__ Out) {
    __shared__ short KT[2][64 * 64];
    __shared__ short VT[2][64 * 64];
    int bh = blockIdx.y, qt = blockIdx.x;
    int b = bh >> 4, h = bh & 15;
    int t = threadIdx.x, wave = t >> 6, lane = t & 63;
    int quad = lane >> 4, l16 = lane & 15;
    const short* Qp = Qb + (size_t)bh * (2048 * 64);
    const short* Kp = Kb + (size_t)bh * (2048 * 64);
    const short* Vp = Vt + (size_t)bh * (64 * 2048);
    int q0 = qt * 64 + wave * 16;

    bf16x8 qf0, qf1;
    {
        const short* qp = Qp + (size_t)(q0 + l16) * 64 + quad * 8;
        qf0 = *(const bf16x8*)qp;
        qf1 = *(const bf16x8*)(qp + 32);
    }
    int r8 = lane >> 3, p8 = lane & 7;
    int kr0 = wave * 16 + r8, kr1 = kr0 + 8;
    int swz0 = (kr0 & 3) | (((kr0 >> 3) & 1) << 2);
    int swz1 = (kr1 & 3) | (((kr1 >> 3) & 1) << 2);
    const short* gk0 = Kp + kr0 * 64 + (p8 ^ swz0) * 8;
    const short* gk1 = Kp + kr1 * 64 + (p8 ^ swz1) * 8;
    const short* gv0 = Vp + kr0 * 2048 + (p8 ^ (kr0 & 7)) * 8;
    const short* gv1 = Vp + kr1 * 2048 + (p8 ^ (kr1 & 7)) * 8;
    int ldsk0 = wave * 1024, ldsk1 = wave * 1024 + 512;
    int swzk = (l16 & 3) | (((l16 >> 2) & 1) << 2);
    int krd = ((l16 >> 2) * 8 + (l16 & 3)) * 64;
    int koff0 = krd + ((quad ^ swzk) * 8);
    int koff1 = krd + (((quad + 4) ^ swzk) * 8);
    int voff0 = l16 * 64 + ((quad ^ (l16 & 7)) * 8);
    int voff1 = l16 * 64 + (((quad + 4) ^ (l16 & 7)) * 8);

    f32x4 o[4] = {};
    f32x4 ol = {};
    bf16x8 ones = {(short)0x3F80, (short)0x3F80, (short)0x3F80, (short)0x3F80,
                   (short)0x3F80, (short)0x3F80, (short)0x3F80, (short)0x3F80};

    gl_lds16(gk0, &KT[0][ldsk0]);
    gl_lds16(gk1, &KT[0][ldsk1]);
    gl_lds16(gv0, &VT[0][ldsk0]);
    gl_lds16(gv1, &VT[0][ldsk1]);

    for (int kt = 0; kt < 32; ++kt) {
        __syncthreads();
        if (kt + 1 < 32) {
            int buf = (kt + 1) & 1;
            gl_lds16(gk0 + (size_t)(kt + 1) * 4096, &KT[buf][ldsk0]);
            gl_lds16(gk1 + (size_t)(kt + 1) * 4096, &KT[buf][ldsk1]);
            gl_lds16(gv0 + (kt + 1) * 64, &VT[buf][ldsk0]);
            gl_lds16(gv1 + (kt + 1) * 64, &VT[buf][ldsk1]);
        }
        const short* kb = &KT[kt & 1][0];
        const short* vb = &VT[kt & 1][0];
        bf16x8 kc[8], vc[8];
#pragma unroll
        for (int hh = 0; hh < 2; ++hh)
#pragma unroll
            for (int ab = 0; ab < 2; ++ab) {
                kc[(hh * 2 + ab) * 2 + 0] = *(const bf16x8*)&kb[koff0 + ab * 256 + hh * 2048];
                kc[(hh * 2 + ab) * 2 + 1] = *(const bf16x8*)&kb[koff1 + ab * 256 + hh * 2048];
            }
#pragma unroll
        for (int hh = 0; hh < 2; ++hh)
#pragma unroll
            for (int dt = 0; dt < 4; ++dt)
                vc[hh * 4 + dt] = *(const bf16x8*)&vb[(hh ? voff1 : voff0) + dt * 1024];

        f32x4 s[4];
#pragma unroll
        for (int i = 0; i < 4; ++i) {
            f32x4 z = {};
            z = __builtin_amdgcn_mfma_f32_16x16x32_bf16(kc[2 * i], qf0, z, 0, 0, 0);
            z = __builtin_amdgcn_mfma_f32_16x16x32_bf16(kc[2 * i + 1], qf1, z, 0, 0, 0);
            s[i] = z;
        }
        bfpack pa0, pa1;
#pragma unroll
        for (int ab = 0; ab < 2; ++ab) {
            float p0 = fast_exp2(s[ab][0]),      p1 = fast_exp2(s[ab][1]);
            float p2 = fast_exp2(s[ab][2]),      p3 = fast_exp2(s[ab][3]);
            float q0e = fast_exp2(s[2 + ab][0]), q1e = fast_exp2(s[2 + ab][1]);
            float q2e = fast_exp2(s[2 + ab][2]), q3e = fast_exp2(s[2 + ab][3]);
            pa0.u[ab * 2 + 0] = pkbf(p0, p1);
            pa0.u[ab * 2 + 1] = pkbf(p2, p3);
            pa1.u[ab * 2 + 0] = pkbf(q0e, q1e);
            pa1.u[ab * 2 + 1] = pkbf(q2e, q3e);
        }
        ol = __builtin_amdgcn_mfma_f32_16x16x32_bf16(pa0.h, ones, ol, 0, 0, 0);
        ol = __builtin_amdgcn_mfma_f32_16x16x32_bf16(pa1.h, ones, ol, 0, 0, 0);
#pragma unroll
        for (int dt = 0; dt < 4; ++dt) {
            o[dt] = __builtin_amdgcn_mfma_f32_16x16x32_bf16(pa0.h, vc[dt],     o[dt], 0, 0, 0);
            o[dt] = __builtin_amdgcn_mfma_f32_16x16x32_bf16(pa1.h, vc[4 + dt], o[dt], 0, 0, 0);
        }
    }

    // ---- fused out-projection epilogue (round-6 verbatim) ----
    short* WsL = &KT[0][0];
    short* myO = &VT[0][wave * 1024];
#pragma unroll
    for (int j = 0; j < 2; ++j) {
        int n = wave * 16 + j * 8 + r8;
        gl_lds16(Wo + (size_t)n * 1024 + h * 64 + ((p8 ^ (n & 7)) * 8),
                 &WsL[(wave * 16 + j * 8) * 64]);
    }
    f32x4 inv;
#pragma unroll
    for (int r = 0; r < 4; ++r) inv[r] = 1.0f / ol[r];
#pragma unroll
    for (int dt = 0; dt < 4; ++dt) {
#pragma unroll
        for (int r = 0; r < 4; ++r) {
            int q = quad * 4 + r;
            int col = dt * 16 + l16;
            int c = col >> 3;
            myO[q * 64 + ((c ^ (q & 7)) * 8) + (col & 7)] = f2bf(o[dt][r] * inv[r]);
        }
    }
    __syncthreads();
    bf16x8 a0 = *(const bf16x8*)&myO[l16 * 64 + ((quad       ^ (l16 & 7)) * 8)];
    bf16x8 a1 = *(const bf16x8*)&myO[l16 * 64 + (((quad + 4) ^ (l16 & 7)) * 8)];
    float* OutRow = Out + ((size_t)(b * 2048 + q0)) * 64;
#pragma unroll
    for (int c = 0; c < 4; ++c) {
        int n = c * 16 + l16;
        bf16x8 b0 = *(const bf16x8*)&WsL[n * 64 + ((quad       ^ (n & 7)) * 8)];
        bf16x8 b1 = *(const bf16x8*)&WsL[n * 64 + (((quad + 4) ^ (n & 7)) * 8)];
        f32x4 rg = {};
        rg = __builtin_amdgcn_mfma_f32_16x16x32_bf16(a0, b0, rg, 0, 0, 0);
        rg = __builtin_amdgcn_mfma_f32_16x16x32_bf16(a1, b1, rg, 0, 0, 0);
#pragma unroll
        for (int r = 0; r < 4; ++r)
            atomicAdd(&OutRow[(quad * 4 + r) * 64 + n], rg[r]);
    }
}

// ---------------------------------------------------------------------------
extern "C" void kernel_launch(void* const* d_in, const int* in_sizes, int n_in,
                              void* d_out, int out_size, void* d_ws, size_t ws_size,
                              hipStream_t stream) {
    const float* A    = (const float*)d_in[0];   // (2,2048,256)
    const float* Wqkv = (const float*)d_in[1];   // (256,3072)
    const float* Wout = (const float*)d_in[2];   // (1024,64)
    float* Out = (float*)d_out;                  // (2,2048,64) fp32

    short* ws = (short*)d_ws;
    short* Wq = ws;                      // (3072,256) bf16
    short* Wo = ws + 786432;             // (64,1024) bf16
    short* Qb = ws + 851968;             // (B,H,N,64)
    short* Kb = ws + 5046272;            // (B,H,N,64)
    short* Vt = ws + 9240576;            // (B,H,64,N)

    hipLaunchKernelGGL(prep_kernel, dim3(256), dim3(256), 0, stream,
                       Wqkv, Wout, Wq, Wo, Out);
    hipLaunchKernelGGL(qkv_kernel, dim3(32, 24), dim3(256), 0, stream,
                       A, Wq, Qb, Kb, Vt);
    hipLaunchKernelGGL(attn_kernel, dim3(32, 32), dim3(256), 0, stream,
                       Qb, Kb, Vt, Wo, Out);
}